// Round 13
// baseline (350.785 us; speedup 1.0000x reference)
//
#include <hip/hip_runtime.h>

#define NN 100000
#define NE 640000
#define NR 3
#define DD 128
#define NSEG (NR * NN)            // 300000 segments (relation, node)
#define NBPR 782                  // buckets per relation (128 nodes each)
#define NBUK (NR * NBPR)          // 2346
#define BCAP 1280                 // per-bucket LDS staging cap (mean 819, sigma 28.6)
#define CHUNK 8192                // edges per partition block
#define NBLK2 ((NR * NE + CHUNK - 1) / CHUNK)   // 235

typedef unsigned int u32;
typedef short bf8_t __attribute__((ext_vector_type(8)));   // 8 bf16 (4 VGPRs)
typedef float f4_t __attribute__((ext_vector_type(4)));

union U4 { uint4 u; bf8_t b; };

__device__ __forceinline__ u32 bfr(float f) {          // f32 -> bf16 bits (RNE)
  u32 u = __float_as_uint(f);
  return (u + 0x7fffu + ((u >> 16) & 1u)) >> 16;
}
__device__ __forceinline__ u32 packbf(float a, float b) {
  return bfr(a) | (bfr(b) << 16);
}
__device__ __forceinline__ float lo16(u32 u) { return __uint_as_float(u << 16); }
__device__ __forceinline__ float hi16(u32 u) { return __uint_as_float(u & 0xffff0000u); }
__device__ __forceinline__ float bf2f(u32 bits) { return __uint_as_float(bits << 16); }

__device__ __forceinline__ bf8_t ldfrag(const u32* p) {
  U4 t; t.u = *(const uint4*)p; return t.b;
}

// async global->LDS, 16B per lane; dest = wave-uniform base + lane*16
__device__ __forceinline__ void gload_lds16(const u32* g, u32* l) {
  __builtin_amdgcn_global_load_lds((const __attribute__((address_space(1))) void*)g,
                                   (__attribute__((address_space(3))) void*)l, 16, 0, 0);
}

// ---------------- x -> packed bf16 ----------------
__global__ __launch_bounds__(256) void convert_x_kernel(const float* __restrict__ x,
                                                        u32* __restrict__ xb) {
  int i = blockIdx.x * 256 + threadIdx.x;
  if (i >= NN * 64) return;
  float2 v = ((const float2*)x)[i];
  xb[i] = packbf(v.x, v.y);
}

// ---------------- pass A: per-block bucket counts (LDS) + src-degree atomics ----------
__global__ __launch_bounds__(512) void count_pass_kernel(const int* __restrict__ src,
                                                         const int* __restrict__ dst,
                                                         int* __restrict__ cnt_out,
                                                         int* __restrict__ cntmat) {
  __shared__ int cnt[NBUK];
  const int tid = threadIdx.x;
  for (int i = tid; i < NBUK; i += 512) cnt[i] = 0;
  __syncthreads();
  const int base = blockIdx.x * CHUNK;
  const int end = min(base + CHUNK, NR * NE);
  for (int i = base + tid; i < end; i += 512) {
    int r = i / NE;
    atomicAdd(&cnt_out[r * NN + src[i]], 1);
    atomicAdd(&cnt[r * NBPR + (dst[i] >> 7)], 1);
  }
  __syncthreads();
  for (int i = tid; i < NBUK; i += 512) cntmat[blockIdx.x * NBUK + i] = cnt[i];
}

// ---------------- rs_out from cnt_out ----------------
__global__ __launch_bounds__(256) void rs_out_kernel(const int* __restrict__ cnt_out,
                                                     float* __restrict__ rs_out) {
  int i = blockIdx.x * 256 + threadIdx.x;
  if (i >= NSEG) return;
  int co = cnt_out[i]; if (co < 1) co = 1;
  rs_out[i] = rsqrtf((float)co);
}

// ---------------- scan across blocks (per bucket) -> cntmat becomes exclusive prefix --
__global__ __launch_bounds__(256) void scan_blocks_kernel(int* __restrict__ cntmat,
                                                          int* __restrict__ btot) {
  __shared__ int s[256];
  const int bk = blockIdx.x;
  const int t = threadIdx.x;
  int v = (t < NBLK2) ? cntmat[t * NBUK + bk] : 0;
  s[t] = v;
  __syncthreads();
  for (int d = 1; d < 256; d <<= 1) {
    int a = (t >= d) ? s[t - d] : 0;
    __syncthreads();
    s[t] += a;
    __syncthreads();
  }
  if (t < NBLK2) cntmat[t * NBUK + bk] = s[t] - v;   // exclusive within bucket
  if (t == 255) btot[bk] = s[255];
}

// ---------------- single-block exclusive scan over bucket totals ----------------
__global__ __launch_bounds__(256) void scan_buckets_kernel(const int* __restrict__ btot,
                                                           int* __restrict__ bucketbase) {
  __shared__ int s[256];
  const int tid = threadIdx.x;
  int v[10]; int loc = 0;
#pragma unroll
  for (int j = 0; j < 10; ++j) {
    int idx = tid * 10 + j;
    int c = (idx < NBUK) ? btot[idx] : 0;
    v[j] = c; loc += c;
  }
  s[tid] = loc;
  __syncthreads();
  for (int d = 1; d < 256; d <<= 1) {
    int t = (tid >= d) ? s[tid - d] : 0;
    __syncthreads();
    s[tid] += t;
    __syncthreads();
  }
  int run = s[tid] - loc;   // exclusive prefix
#pragma unroll
  for (int j = 0; j < 10; ++j) {
    int idx = tid * 10 + j;
    if (idx < NBUK) bucketbase[idx] = run;
    run += v[j];
  }
  if (tid == 255) bucketbase[NBUK] = s[255];
}

// ---------------- pass B: deterministic placement into bucket-grouped payload ---------
__global__ __launch_bounds__(512) void place_pass_kernel(const int* __restrict__ src,
                                                         const int* __restrict__ dst,
                                                         const int* __restrict__ cntmat,
                                                         const int* __restrict__ bucketbase,
                                                         u32* __restrict__ bucketbuf) {
  __shared__ int cur[NBUK];
  const int tid = threadIdx.x;
  for (int i = tid; i < NBUK; i += 512)
    cur[i] = bucketbase[i] + cntmat[blockIdx.x * NBUK + i];
  __syncthreads();
  const int base = blockIdx.x * CHUNK;
  const int end = min(base + CHUNK, NR * NE);
  for (int i = base + tid; i < end; i += 512) {
    int r = i / NE;
    int d = dst[i];
    int bk = r * NBPR + (d >> 7);
    int pos = atomicAdd(&cur[bk], 1);       // LDS returning atomic, low contention
    bucketbuf[pos] = (u32)src[i] | ((u32)(d & 127) << 17);
  }
}

// ---------------- fused: in-bucket counting sort + rs_in + gather aggregate -----------
// rsL: per-edge rs_out gathered during the (parallel) scatter phase, so the
// gather-FMA loop's dependent chain is LDS -> row-load -> FMA only.
__global__ __launch_bounds__(256) void bucket_aggregate_kernel(
    const u32* __restrict__ xb, const u32* __restrict__ bucketbuf,
    const int* __restrict__ bucketbase, const float* __restrict__ rs_out,
    float* __restrict__ rs_in, u32* __restrict__ aggb) {
  __shared__ u32 eL[BCAP];
  __shared__ u32 sorted[BCAP];
  __shared__ float rsL[BCAP];
  __shared__ int cntA[128], prefE[128], cur[128];
  const int tid = threadIdx.x;
  const int bk = blockIdx.x;
  const int r = bk / NBPR, bidx = bk % NBPR;
  const int node0 = bidx * 128;
  const int base = bucketbase[bk];
  const int count = min(bucketbase[bk + 1] - base, BCAP);
  const float* rsb = rs_out + r * NN;
  if (tid < 128) cntA[tid] = 0;
  for (int i = tid; i < count; i += 256) eL[i] = bucketbuf[base + i];
  __syncthreads();
  for (int i = tid; i < count; i += 256) atomicAdd(&cntA[eL[i] >> 17], 1);
  __syncthreads();
  if (tid < 128) prefE[tid] = cntA[tid];
  __syncthreads();
  for (int d = 1; d < 128; d <<= 1) {
    int v = 0;
    if (tid < 128 && tid >= d) v = prefE[tid - d];
    __syncthreads();
    if (tid < 128) prefE[tid] += v;
    __syncthreads();
  }
  if (tid < 128) {
    int excl = prefE[tid] - cntA[tid];
    prefE[tid] = excl;
    cur[tid] = excl;
    int node = node0 + tid;
    if (node < NN) rs_in[r * NN + node] = rsqrtf((float)max(cntA[tid], 1));
  }
  __syncthreads();
  for (int i = tid; i < count; i += 256) {
    u32 v = eL[i];
    int pos = atomicAdd(&cur[v >> 17], 1);
    int s = (int)(v & 0x1FFFFu);
    sorted[pos] = (u32)s;
    rsL[pos] = rsb[s];          // parallel rs gather, off the FMA critical chain
  }
  __syncthreads();

  // gather-aggregate: 16-lane groups, one node at a time, register f32 accum
  const int l16 = tid & 15, g = tid >> 4;
  for (int nn = g; nn < 128; nn += 16) {
    const int node = node0 + nn;
    if (node >= NN) continue;
    const int beg = prefE[nn], cE = cntA[nn];
    float a[8] = {0.f, 0.f, 0.f, 0.f, 0.f, 0.f, 0.f, 0.f};
    int e = 0;
    for (; e + 3 < cE; e += 4) {
      int s0 = (int)sorted[beg + e],     s1 = (int)sorted[beg + e + 1];
      int s2 = (int)sorted[beg + e + 2], s3 = (int)sorted[beg + e + 3];
      float c0 = rsL[beg + e],     c1 = rsL[beg + e + 1];
      float c2 = rsL[beg + e + 2], c3 = rsL[beg + e + 3];
      uint4 u0 = *(const uint4*)&xb[(size_t)s0 * 64 + l16 * 4];
      uint4 u1 = *(const uint4*)&xb[(size_t)s1 * 64 + l16 * 4];
      uint4 u2 = *(const uint4*)&xb[(size_t)s2 * 64 + l16 * 4];
      uint4 u3 = *(const uint4*)&xb[(size_t)s3 * 64 + l16 * 4];
      a[0] = fmaf(lo16(u0.x), c0, a[0]); a[1] = fmaf(hi16(u0.x), c0, a[1]);
      a[2] = fmaf(lo16(u0.y), c0, a[2]); a[3] = fmaf(hi16(u0.y), c0, a[3]);
      a[4] = fmaf(lo16(u0.z), c0, a[4]); a[5] = fmaf(hi16(u0.z), c0, a[5]);
      a[6] = fmaf(lo16(u0.w), c0, a[6]); a[7] = fmaf(hi16(u0.w), c0, a[7]);
      a[0] = fmaf(lo16(u1.x), c1, a[0]); a[1] = fmaf(hi16(u1.x), c1, a[1]);
      a[2] = fmaf(lo16(u1.y), c1, a[2]); a[3] = fmaf(hi16(u1.y), c1, a[3]);
      a[4] = fmaf(lo16(u1.z), c1, a[4]); a[5] = fmaf(hi16(u1.z), c1, a[5]);
      a[6] = fmaf(lo16(u1.w), c1, a[6]); a[7] = fmaf(hi16(u1.w), c1, a[7]);
      a[0] = fmaf(lo16(u2.x), c2, a[0]); a[1] = fmaf(hi16(u2.x), c2, a[1]);
      a[2] = fmaf(lo16(u2.y), c2, a[2]); a[3] = fmaf(hi16(u2.y), c2, a[3]);
      a[4] = fmaf(lo16(u2.z), c2, a[4]); a[5] = fmaf(hi16(u2.z), c2, a[5]);
      a[6] = fmaf(lo16(u2.w), c2, a[6]); a[7] = fmaf(hi16(u2.w), c2, a[7]);
      a[0] = fmaf(lo16(u3.x), c3, a[0]); a[1] = fmaf(hi16(u3.x), c3, a[1]);
      a[2] = fmaf(lo16(u3.y), c3, a[2]); a[3] = fmaf(hi16(u3.y), c3, a[3]);
      a[4] = fmaf(lo16(u3.z), c3, a[4]); a[5] = fmaf(hi16(u3.z), c3, a[5]);
      a[6] = fmaf(lo16(u3.w), c3, a[6]); a[7] = fmaf(hi16(u3.w), c3, a[7]);
    }
    for (; e < cE; ++e) {
      int s0 = (int)sorted[beg + e];
      float c0 = rsL[beg + e];
      uint4 u0 = *(const uint4*)&xb[(size_t)s0 * 64 + l16 * 4];
      a[0] = fmaf(lo16(u0.x), c0, a[0]); a[1] = fmaf(hi16(u0.x), c0, a[1]);
      a[2] = fmaf(lo16(u0.y), c0, a[2]); a[3] = fmaf(hi16(u0.y), c0, a[3]);
      a[4] = fmaf(lo16(u0.z), c0, a[4]); a[5] = fmaf(hi16(u0.z), c0, a[5]);
      a[6] = fmaf(lo16(u0.w), c0, a[6]); a[7] = fmaf(hi16(u0.w), c0, a[7]);
    }
    uint4 o;
    o.x = packbf(a[0], a[1]);
    o.y = packbf(a[2], a[3]);
    o.z = packbf(a[4], a[5]);
    o.w = packbf(a[6], a[7]);
    *(uint4*)&aggb[((size_t)r * NN + node) * 64 + l16 * 4] = o;
  }
}

// ---------------- prep 1: WWa1[r] = W[r] @ Wa1 (f32) ----------------
__global__ __launch_bounds__(256) void prep_wwa1_kernel(const float* __restrict__ W,
                                                        const float* __restrict__ Wa1,
                                                        float* __restrict__ WWa1) {
  int idx = blockIdx.x * 256 + threadIdx.x;       // r*16384 + i*128 + c
  if (idx >= NR * DD * DD) return;
  int r = idx >> 14, rem = idx & 16383, i = rem >> 7, c = rem & 127;
  const float* wrow = W + (r << 14) + (i << 7);
  float s = 0.f;
#pragma unroll 8
  for (int k = 0; k < DD; ++k) s = fmaf(wrow[k], Wa1[k * DD + c], s);
  WWa1[idx] = s;
}

// ---------------- prep 2: transpose + bf16 hi/lo split, fragment-ready -----------------
__global__ __launch_bounds__(256) void prep_pack_kernel(const float* __restrict__ W,
                                                        const float* __restrict__ WWa1,
                                                        u32* __restrict__ wt_hi,
                                                        u32* __restrict__ wt_lo,
                                                        u32* __restrict__ wwt_hi) {
  int idx = blockIdx.x * 256 + threadIdx.x;       // r*8192 + n*64 + ku
  if (idx >= NR * DD * 64) return;
  int r = idx >> 13, rem = idx & 8191, n = rem >> 6, ku = rem & 63;
  int k0 = ku * 2;
  {
    const float* M = W + (r << 14);
    float w0 = M[k0 * DD + n], w1 = M[(k0 + 1) * DD + n];
    u32 h0 = bfr(w0), h1 = bfr(w1);
    float l0 = w0 - bf2f(h0), l1 = w1 - bf2f(h1);
    wt_hi[idx] = h0 | (h1 << 16);
    wt_lo[idx] = packbf(l0, l1);
  }
  {
    const float* M = WWa1 + (r << 14);
    float w0 = M[k0 * DD + n], w1 = M[(k0 + 1) * DD + n];
    wwt_hi[idx] = bfr(w0) | (bfr(w1) << 16);
  }
}

// ---------------- prep 3: bsum[r][c] = (b_r @ Wa1)[c] + ba1[c] ----------------
__global__ __launch_bounds__(256) void prep_bsum_kernel(const float* __restrict__ b,
                                                        const float* __restrict__ Wa1,
                                                        const float* __restrict__ ba1,
                                                        float* __restrict__ bsum) {
  int idx = blockIdx.x * 256 + threadIdx.x;       // r*128 + c
  if (idx >= NR * DD) return;
  int r = idx >> 7, c = idx & 127;
  float s = ba1[c];
#pragma unroll 8
  for (int k = 0; k < DD; ++k) s = fmaf(b[r * DD + k], Wa1[k * DD + c], s);
  bsum[idx] = s;
}

#define MFMA(a, b, c) __builtin_amdgcn_mfma_f32_16x16x32_bf16((a), (b), (c), 0, 0, 0)

// ============ pass 1: scores + softmax -> e[3][N], w[3][N]=e*rs_in ============
__global__ __launch_bounds__(256, 2) void score_pass_kernel(
    const u32* __restrict__ aggb, const u32* __restrict__ wwt_hi,
    const float* __restrict__ rs_in, const float* __restrict__ bsum,
    const float* __restrict__ wa2, float* __restrict__ evec,
    float* __restrict__ wvec) {
  __shared__ u32 As[8192];   // 128 rows x 16 chunks(16B), chunk ^= (row&7)
  __shared__ u32 Bs[8192];
  __shared__ float scoreS[NR][2][128];
  const int tid = threadIdx.x;
  const int l = tid & 63, w = tid >> 6;
  const int wr = w >> 1, wc = w & 1;
  const int l15 = l & 15, lg = l >> 4;
  const int row0 = blockIdx.x * 128;

  float wa2v[4];
#pragma unroll
  for (int nf = 0; nf < 4; ++nf) wa2v[nf] = wa2[wc * 64 + nf * 16 + l15];

  for (int r = 0; r < NR; ++r) {
    if (r) __syncthreads();
    const u32* Ar = aggb + (size_t)r * NN * 64;
    const u32* Br = wwt_hi + (size_t)r * 8192;
#pragma unroll
    for (int it = 0; it < 8; ++it) {
      int s = it * 256 + tid;            // 16B-chunk slot 0..2047
      int row = s >> 4;
      int c = (s & 15) ^ (row & 7);      // inverse-swizzled source chunk
      int grow = min(row0 + row, NN - 1);
      gload_lds16(Ar + (size_t)grow * 64 + c * 4, &As[it * 1024 + w * 256]);
      gload_lds16(Br + row * 64 + c * 4, &Bs[it * 1024 + w * 256]);
    }
    __syncthreads();

    f4_t c2[4][4];
#pragma unroll
    for (int rf = 0; rf < 4; ++rf)
#pragma unroll
      for (int nf = 0; nf < 4; ++nf) c2[rf][nf] = (f4_t)0.f;

#pragma unroll
    for (int ks = 0; ks < 4; ++ks) {
      bf8_t a[4];
#pragma unroll
      for (int rf = 0; rf < 4; ++rf) {
        int m = wr * 64 + rf * 16 + l15;
        int ch = (ks * 4 + lg) ^ (m & 7);
        a[rf] = ldfrag(&As[m * 64 + ch * 4]);
      }
#pragma unroll
      for (int nf = 0; nf < 4; ++nf) {
        int n = wc * 64 + nf * 16 + l15;
        int ch = (ks * 4 + lg) ^ (n & 7);
        bf8_t bb = ldfrag(&Bs[n * 64 + ch * 4]);
#pragma unroll
        for (int rf = 0; rf < 4; ++rf) c2[rf][nf] = MFMA(a[rf], bb, c2[rf][nf]);
      }
    }

    // epilogue: score partials
#pragma unroll
    for (int rf = 0; rf < 4; ++rf) {
      const int lr0 = wr * 64 + rf * 16 + lg * 4;
      float rsv[4];
#pragma unroll
      for (int reg = 0; reg < 4; ++reg)
        rsv[reg] = rs_in[r * NN + min(row0 + lr0 + reg, NN - 1)];
      float part[4] = {0.f, 0.f, 0.f, 0.f};
#pragma unroll
      for (int nf = 0; nf < 4; ++nf) {
        int col = wc * 64 + nf * 16 + l15;
        float bs = bsum[r * DD + col];
#pragma unroll
        for (int reg = 0; reg < 4; ++reg) {
          float t = fmaf(c2[rf][nf][reg], rsv[reg], bs);
          t = fminf(fmaxf(t, -15.f), 15.f);
          float ex = __expf(2.f * t);
          part[reg] = fmaf((ex - 1.f) / (ex + 1.f), wa2v[nf], part[reg]);
        }
      }
#pragma unroll
      for (int reg = 0; reg < 4; ++reg) {
        float p = part[reg];
        p += __shfl_xor(p, 1);
        p += __shfl_xor(p, 2);
        p += __shfl_xor(p, 4);
        p += __shfl_xor(p, 8);
        if (l15 == 0) scoreS[r][wc][lr0 + reg] = p;
      }
    }
  }
  __syncthreads();
  if (tid < 128) {
    int grow = row0 + tid;
    if (grow < NN) {
      float s0 = scoreS[0][0][tid] + scoreS[0][1][tid];
      float s1 = scoreS[1][0][tid] + scoreS[1][1][tid];
      float s2 = scoreS[2][0][tid] + scoreS[2][1][tid];
      float mx = fmaxf(s0, fmaxf(s1, s2));
      float e0 = __expf(s0 - mx), e1 = __expf(s1 - mx), e2 = __expf(s2 - mx);
      float inv = 1.f / (e0 + e1 + e2);
      e0 *= inv; e1 *= inv; e2 *= inv;
      evec[grow] = e0; evec[NN + grow] = e1; evec[2 * NN + grow] = e2;
      wvec[grow]          = e0 * rs_in[grow];
      wvec[NN + grow]     = e1 * rs_in[NN + grow];
      wvec[2 * NN + grow] = e2 * rs_in[2 * NN + grow];
    }
  }
}

// ============ pass 2: out = sum_r w_r*(agg_r @ W_r) + sum_r e_r*b_r ============
// As enlarged to 8320 u32: staging uses [0,8192); epilogue reuses it (stride 130)
// as a 64x128 f32 tile for coalesced float4 output stores.
__global__ __launch_bounds__(256, 2) void out_pass_kernel(
    const u32* __restrict__ aggb, const u32* __restrict__ wt_hi,
    const u32* __restrict__ wt_lo, const float* __restrict__ evec,
    const float* __restrict__ wvec, const float* __restrict__ bias,
    float* __restrict__ out) {
  __shared__ u32 As[8320];
  __shared__ u32 Bs[8192];       // wt_hi (swizzled); wt_lo comes from global
  __shared__ float eL[NR][128];
  __shared__ float wfL[NR][128];
  __shared__ float bL[NR][128];
  const int tid = threadIdx.x;
  const int l = tid & 63, w = tid >> 6;
  const int wr = w >> 1, wc = w & 1;
  const int l15 = l & 15, lg = l >> 4;
  const int row0 = blockIdx.x * 128;

  // stage per-row softmax weights and bias (once, covered by first barrier)
  if (tid < 128) {
    int grow = min(row0 + tid, NN - 1);
#pragma unroll
    for (int r = 0; r < NR; ++r) {
      eL[r][tid]  = evec[r * NN + grow];
      wfL[r][tid] = wvec[r * NN + grow];
    }
  }
  for (int idx = tid; idx < NR * DD; idx += 256) bL[idx >> 7][idx & 127] = bias[idx];

  f4_t fo[4][4];

  for (int r = 0; r < NR; ++r) {
    if (r) __syncthreads();
    const u32* Ar = aggb + (size_t)r * NN * 64;
    const u32* Br = wt_hi + (size_t)r * 8192;
#pragma unroll
    for (int it = 0; it < 8; ++it) {
      int s = it * 256 + tid;
      int row = s >> 4;
      int c = (s & 15) ^ (row & 7);
      int grow = min(row0 + row, NN - 1);
      gload_lds16(Ar + (size_t)grow * 64 + c * 4, &As[it * 1024 + w * 256]);
      gload_lds16(Br + row * 64 + c * 4, &Bs[it * 1024 + w * 256]);
    }
    __syncthreads();

    if (r == 0) {
      // init accumulator with the softmax-weighted bias term
#pragma unroll
      for (int rf = 0; rf < 4; ++rf) {
        const int lr0 = wr * 64 + rf * 16 + lg * 4;
#pragma unroll
        for (int nf = 0; nf < 4; ++nf) {
          const int col = wc * 64 + nf * 16 + l15;
#pragma unroll
          for (int reg = 0; reg < 4; ++reg) {
            float v = eL[0][lr0 + reg] * bL[0][col];
            v = fmaf(eL[1][lr0 + reg], bL[1][col], v);
            v = fmaf(eL[2][lr0 + reg], bL[2][col], v);
            fo[rf][nf][reg] = v;
          }
        }
      }
    }

    f4_t cc[4][4];
#pragma unroll
    for (int rf = 0; rf < 4; ++rf)
#pragma unroll
      for (int nf = 0; nf < 4; ++nf) cc[rf][nf] = (f4_t)0.f;

#pragma unroll
    for (int ks = 0; ks < 4; ++ks) {
      bf8_t a[4];
#pragma unroll
      for (int rf = 0; rf < 4; ++rf) {
        int m = wr * 64 + rf * 16 + l15;
        int ch = (ks * 4 + lg) ^ (m & 7);
        a[rf] = ldfrag(&As[m * 64 + ch * 4]);
      }
#pragma unroll
      for (int nf = 0; nf < 4; ++nf) {
        int n = wc * 64 + nf * 16 + l15;
        int ch = (ks * 4 + lg) ^ (n & 7);
        bf8_t bh = ldfrag(&Bs[n * 64 + ch * 4]);
        bf8_t bl = ldfrag(wt_lo + (size_t)r * 8192 + n * 64 + (ks * 4 + lg) * 4);
#pragma unroll
        for (int rf = 0; rf < 4; ++rf) cc[rf][nf] = MFMA(a[rf], bh, cc[rf][nf]);
#pragma unroll
        for (int rf = 0; rf < 4; ++rf) cc[rf][nf] = MFMA(a[rf], bl, cc[rf][nf]);
      }
    }

    // fo += w_r(row) * cc
#pragma unroll
    for (int rf = 0; rf < 4; ++rf) {
      const int lr0 = wr * 64 + rf * 16 + lg * 4;
#pragma unroll
      for (int nf = 0; nf < 4; ++nf)
#pragma unroll
        for (int reg = 0; reg < 4; ++reg)
          fo[rf][nf][reg] = fmaf(cc[rf][nf][reg], wfL[r][lr0 + reg], fo[rf][nf][reg]);
    }
  }

  // ---- staged coalesced store: two 64-row halves through As (stride 130 f32) ----
  __syncthreads();   // all MFMA reads of As complete
  float* Asf = (float*)As;
  const int rloc = tid >> 2;          // 0..63
  const int c0 = (tid & 3) * 32;      // 0,32,64,96
#pragma unroll
  for (int half = 0; half < 2; ++half) {
    if (wr == half) {
#pragma unroll
      for (int rf = 0; rf < 4; ++rf)
#pragma unroll
        for (int nf = 0; nf < 4; ++nf)
#pragma unroll
          for (int reg = 0; reg < 4; ++reg)
            Asf[(rf * 16 + lg * 4 + reg) * 130 + wc * 64 + nf * 16 + l15] =
                fo[rf][nf][reg];
    }
    __syncthreads();
    int grow = row0 + half * 64 + rloc;
    if (grow < NN) {
#pragma unroll
      for (int j = 0; j < 8; ++j) {
        float4 v = *(const float4*)&Asf[rloc * 130 + c0 + j * 4];
        *(float4*)&out[(size_t)grow * DD + c0 + j * 4] = v;
      }
    }
    __syncthreads();
  }
}

extern "C" void kernel_launch(void* const* d_in, const int* in_sizes, int n_in,
                              void* d_out, int out_size, void* d_ws, size_t ws_size,
                              hipStream_t stream) {
  const float* x   = (const float*)d_in[0];
  const int*   src = (const int*)d_in[1];
  const int*   dst = (const int*)d_in[2];
  const float* W   = (const float*)d_in[3];
  const float* b   = (const float*)d_in[4];
  const float* Wa1 = (const float*)d_in[5];
  const float* ba1 = (const float*)d_in[6];
  const float* wa2 = (const float*)d_in[7];
  float* out = (float*)d_out;

  char* ws = (char*)d_ws;
  size_t off = 0;
  u32* aggb = (u32*)(ws + off); off += (size_t)NSEG * 64 * 4;   // 76.8 MB
  u32* xb   = (u32*)(ws + off); off += (size_t)NN * 64 * 4;     // 25.6 MB
  u32* bucketbuf = (u32*)(ws + off); off += (size_t)NR * NE * 4;  // 7.68 MB (exact)
  int* cntmat  = (int*)(ws + off); off += (size_t)NBLK2 * NBUK * 4;  // 2.2 MB
  int* cnt_out = (int*)(ws + off); off += (size_t)NSEG * 4;
  float* rs_out = (float*)(ws + off); off += (size_t)NSEG * 4;
  float* rs_in  = (float*)(ws + off); off += (size_t)NSEG * 4;
  float* evec   = (float*)(ws + off); off += (size_t)NSEG * 4;
  float* wvec   = (float*)(ws + off); off += (size_t)NSEG * 4;
  int* btot       = (int*)(ws + off); off += (size_t)NBUK * 4;
  int* bucketbase = (int*)(ws + off); off += (size_t)(NBUK + 4) * 4;
  float* WWa1  = (float*)(ws + off); off += (size_t)NR * DD * DD * 4;
  u32* wt_hi   = (u32*)(ws + off); off += (size_t)NR * DD * 64 * 4;
  u32* wt_lo   = (u32*)(ws + off); off += (size_t)NR * DD * 64 * 4;
  u32* wwt_hi  = (u32*)(ws + off); off += (size_t)NR * DD * 64 * 4;
  float* bsum  = (float*)(ws + off); off += (size_t)NR * DD * 4;
  if (ws_size < off) return;  // fail loudly (output stays poisoned)

  hipMemsetAsync(cnt_out, 0, (size_t)NSEG * 4, stream);

  // weight prep (independent of graph chain)
  prep_wwa1_kernel<<<(NR * DD * DD + 255) / 256, 256, 0, stream>>>(W, Wa1, WWa1);
  prep_pack_kernel<<<(NR * DD * 64 + 255) / 256, 256, 0, stream>>>(W, WWa1, wt_hi, wt_lo,
                                                                   wwt_hi);
  prep_bsum_kernel<<<(NR * DD + 255) / 256, 256, 0, stream>>>(b, Wa1, ba1, bsum);

  convert_x_kernel<<<(NN * 64 + 255) / 256, 256, 0, stream>>>(x, xb);
  count_pass_kernel<<<NBLK2, 512, 0, stream>>>(src, dst, cnt_out, cntmat);
  rs_out_kernel<<<(NSEG + 255) / 256, 256, 0, stream>>>(cnt_out, rs_out);
  scan_blocks_kernel<<<NBUK, 256, 0, stream>>>(cntmat, btot);
  scan_buckets_kernel<<<1, 256, 0, stream>>>(btot, bucketbase);
  place_pass_kernel<<<NBLK2, 512, 0, stream>>>(src, dst, cntmat, bucketbase, bucketbuf);
  bucket_aggregate_kernel<<<NBUK, 256, 0, stream>>>(xb, bucketbuf, bucketbase, rs_out,
                                                    rs_in, aggb);

  int gb = (NN + 127) / 128;
  score_pass_kernel<<<gb, 256, 0, stream>>>(aggb, wwt_hi, rs_in, bsum, wa2, evec, wvec);
  out_pass_kernel<<<gb, 256, 0, stream>>>(aggb, wt_hi, wt_lo, evec, wvec, b, out);
}

// Round 14
// 341.425 us; speedup vs baseline: 1.0274x; 1.0274x over previous
//
#include <hip/hip_runtime.h>

#define NN 100000
#define NE 640000
#define NR 3
#define DD 128
#define NSEG (NR * NN)            // 300000 segments (relation, node)
#define NBPR 782                  // buckets per relation (128 nodes each)
#define NBUK (NR * NBPR)          // 2346
#define BCAP 1280                 // per-bucket LDS staging cap (mean 819, sigma 28.6)
#define CHUNK 8192                // edges per partition block
#define NBLK2 ((NR * NE + CHUNK - 1) / CHUNK)   // 235

typedef unsigned int u32;
typedef short bf8_t __attribute__((ext_vector_type(8)));   // 8 bf16 (4 VGPRs)
typedef float f4_t __attribute__((ext_vector_type(4)));

union U4 { uint4 u; bf8_t b; };

__device__ __forceinline__ u32 bfr(float f) {          // f32 -> bf16 bits (RNE)
  u32 u = __float_as_uint(f);
  return (u + 0x7fffu + ((u >> 16) & 1u)) >> 16;
}
__device__ __forceinline__ u32 packbf(float a, float b) {
  return bfr(a) | (bfr(b) << 16);
}
__device__ __forceinline__ float lo16(u32 u) { return __uint_as_float(u << 16); }
__device__ __forceinline__ float hi16(u32 u) { return __uint_as_float(u & 0xffff0000u); }
__device__ __forceinline__ float bf2f(u32 bits) { return __uint_as_float(bits << 16); }

__device__ __forceinline__ bf8_t ldfrag(const u32* p) {
  U4 t; t.u = *(const uint4*)p; return t.b;
}

// async global->LDS, 16B per lane; dest = wave-uniform base + lane*16
__device__ __forceinline__ void gload_lds16(const u32* g, u32* l) {
  __builtin_amdgcn_global_load_lds((const __attribute__((address_space(1))) void*)g,
                                   (__attribute__((address_space(3))) void*)l, 16, 0, 0);
}

// ---------------- x -> packed bf16 ----------------
__global__ __launch_bounds__(256) void convert_x_kernel(const float* __restrict__ x,
                                                        u32* __restrict__ xb) {
  int i = blockIdx.x * 256 + threadIdx.x;
  if (i >= NN * 64) return;
  float2 v = ((const float2*)x)[i];
  xb[i] = packbf(v.x, v.y);
}

// ---------------- pass A: per-block bucket counts (LDS) + src-degree atomics ----------
__global__ __launch_bounds__(512) void count_pass_kernel(const int* __restrict__ src,
                                                         const int* __restrict__ dst,
                                                         int* __restrict__ cnt_out,
                                                         int* __restrict__ cntmat) {
  __shared__ int cnt[NBUK];
  const int tid = threadIdx.x;
  for (int i = tid; i < NBUK; i += 512) cnt[i] = 0;
  __syncthreads();
  const int base = blockIdx.x * CHUNK;
  const int end = min(base + CHUNK, NR * NE);
  for (int i = base + tid; i < end; i += 512) {
    int r = i / NE;
    atomicAdd(&cnt_out[r * NN + src[i]], 1);
    atomicAdd(&cnt[r * NBPR + (dst[i] >> 7)], 1);
  }
  __syncthreads();
  for (int i = tid; i < NBUK; i += 512) cntmat[blockIdx.x * NBUK + i] = cnt[i];
}

// ---------------- rs_out from cnt_out ----------------
__global__ __launch_bounds__(256) void rs_out_kernel(const int* __restrict__ cnt_out,
                                                     float* __restrict__ rs_out) {
  int i = blockIdx.x * 256 + threadIdx.x;
  if (i >= NSEG) return;
  int co = cnt_out[i]; if (co < 1) co = 1;
  rs_out[i] = rsqrtf((float)co);
}

// ---------------- scan across blocks (per bucket) -> cntmat becomes exclusive prefix --
__global__ __launch_bounds__(256) void scan_blocks_kernel(int* __restrict__ cntmat,
                                                          int* __restrict__ btot) {
  __shared__ int s[256];
  const int bk = blockIdx.x;
  const int t = threadIdx.x;
  int v = (t < NBLK2) ? cntmat[t * NBUK + bk] : 0;
  s[t] = v;
  __syncthreads();
  for (int d = 1; d < 256; d <<= 1) {
    int a = (t >= d) ? s[t - d] : 0;
    __syncthreads();
    s[t] += a;
    __syncthreads();
  }
  if (t < NBLK2) cntmat[t * NBUK + bk] = s[t] - v;   // exclusive within bucket
  if (t == 255) btot[bk] = s[255];
}

// ---------------- single-block exclusive scan over bucket totals ----------------
__global__ __launch_bounds__(256) void scan_buckets_kernel(const int* __restrict__ btot,
                                                           int* __restrict__ bucketbase) {
  __shared__ int s[256];
  const int tid = threadIdx.x;
  int v[10]; int loc = 0;
#pragma unroll
  for (int j = 0; j < 10; ++j) {
    int idx = tid * 10 + j;
    int c = (idx < NBUK) ? btot[idx] : 0;
    v[j] = c; loc += c;
  }
  s[tid] = loc;
  __syncthreads();
  for (int d = 1; d < 256; d <<= 1) {
    int t = (tid >= d) ? s[tid - d] : 0;
    __syncthreads();
    s[tid] += t;
    __syncthreads();
  }
  int run = s[tid] - loc;   // exclusive prefix
#pragma unroll
  for (int j = 0; j < 10; ++j) {
    int idx = tid * 10 + j;
    if (idx < NBUK) bucketbase[idx] = run;
    run += v[j];
  }
  if (tid == 255) bucketbase[NBUK] = s[255];
}

// ---------------- pass B: deterministic placement into bucket-grouped payload ---------
__global__ __launch_bounds__(512) void place_pass_kernel(const int* __restrict__ src,
                                                         const int* __restrict__ dst,
                                                         const int* __restrict__ cntmat,
                                                         const int* __restrict__ bucketbase,
                                                         u32* __restrict__ bucketbuf) {
  __shared__ int cur[NBUK];
  const int tid = threadIdx.x;
  for (int i = tid; i < NBUK; i += 512)
    cur[i] = bucketbase[i] + cntmat[blockIdx.x * NBUK + i];
  __syncthreads();
  const int base = blockIdx.x * CHUNK;
  const int end = min(base + CHUNK, NR * NE);
  for (int i = base + tid; i < end; i += 512) {
    int r = i / NE;
    int d = dst[i];
    int bk = r * NBPR + (d >> 7);
    int pos = atomicAdd(&cur[bk], 1);       // LDS returning atomic, low contention
    bucketbuf[pos] = (u32)src[i] | ((u32)(d & 127) << 17);
  }
}

// ---------------- fused: in-bucket counting sort + rs_in + gather aggregate -----------
__global__ __launch_bounds__(256) void bucket_aggregate_kernel(
    const u32* __restrict__ xb, const u32* __restrict__ bucketbuf,
    const int* __restrict__ bucketbase, const float* __restrict__ rs_out,
    float* __restrict__ rs_in, u32* __restrict__ aggb) {
  __shared__ u32 eL[BCAP];
  __shared__ u32 sorted[BCAP];
  __shared__ int cntA[128], prefE[128], cur[128];
  const int tid = threadIdx.x;
  const int bk = blockIdx.x;
  const int r = bk / NBPR, bidx = bk % NBPR;
  const int node0 = bidx * 128;
  const int base = bucketbase[bk];
  const int count = min(bucketbase[bk + 1] - base, BCAP);
  if (tid < 128) cntA[tid] = 0;
  for (int i = tid; i < count; i += 256) eL[i] = bucketbuf[base + i];
  __syncthreads();
  for (int i = tid; i < count; i += 256) atomicAdd(&cntA[eL[i] >> 17], 1);
  __syncthreads();
  if (tid < 128) prefE[tid] = cntA[tid];
  __syncthreads();
  for (int d = 1; d < 128; d <<= 1) {
    int v = 0;
    if (tid < 128 && tid >= d) v = prefE[tid - d];
    __syncthreads();
    if (tid < 128) prefE[tid] += v;
    __syncthreads();
  }
  if (tid < 128) {
    int excl = prefE[tid] - cntA[tid];
    prefE[tid] = excl;
    cur[tid] = excl;
    int node = node0 + tid;
    if (node < NN) rs_in[r * NN + node] = rsqrtf((float)max(cntA[tid], 1));
  }
  __syncthreads();
  for (int i = tid; i < count; i += 256) {
    u32 v = eL[i];
    int pos = atomicAdd(&cur[v >> 17], 1);
    sorted[pos] = v & 0x1FFFFu;
  }
  __syncthreads();

  // gather-aggregate: 16-lane groups, one node at a time, register f32 accum
  const int l16 = tid & 15, g = tid >> 4;
  const float* rsb = rs_out + r * NN;
  for (int nn = g; nn < 128; nn += 16) {
    const int node = node0 + nn;
    if (node >= NN) continue;
    const int beg = prefE[nn], cE = cntA[nn];
    float a[8] = {0.f, 0.f, 0.f, 0.f, 0.f, 0.f, 0.f, 0.f};
    int e = 0;
    for (; e + 1 < cE; e += 2) {
      int s0 = (int)sorted[beg + e], s1 = (int)sorted[beg + e + 1];
      float c0 = rsb[s0], c1 = rsb[s1];
      uint4 u0 = *(const uint4*)&xb[(size_t)s0 * 64 + l16 * 4];
      uint4 u1 = *(const uint4*)&xb[(size_t)s1 * 64 + l16 * 4];
      a[0] = fmaf(lo16(u0.x), c0, a[0]); a[1] = fmaf(hi16(u0.x), c0, a[1]);
      a[2] = fmaf(lo16(u0.y), c0, a[2]); a[3] = fmaf(hi16(u0.y), c0, a[3]);
      a[4] = fmaf(lo16(u0.z), c0, a[4]); a[5] = fmaf(hi16(u0.z), c0, a[5]);
      a[6] = fmaf(lo16(u0.w), c0, a[6]); a[7] = fmaf(hi16(u0.w), c0, a[7]);
      a[0] = fmaf(lo16(u1.x), c1, a[0]); a[1] = fmaf(hi16(u1.x), c1, a[1]);
      a[2] = fmaf(lo16(u1.y), c1, a[2]); a[3] = fmaf(hi16(u1.y), c1, a[3]);
      a[4] = fmaf(lo16(u1.z), c1, a[4]); a[5] = fmaf(hi16(u1.z), c1, a[5]);
      a[6] = fmaf(lo16(u1.w), c1, a[6]); a[7] = fmaf(hi16(u1.w), c1, a[7]);
    }
    if (e < cE) {
      int s0 = (int)sorted[beg + e];
      float c0 = rsb[s0];
      uint4 u0 = *(const uint4*)&xb[(size_t)s0 * 64 + l16 * 4];
      a[0] = fmaf(lo16(u0.x), c0, a[0]); a[1] = fmaf(hi16(u0.x), c0, a[1]);
      a[2] = fmaf(lo16(u0.y), c0, a[2]); a[3] = fmaf(hi16(u0.y), c0, a[3]);
      a[4] = fmaf(lo16(u0.z), c0, a[4]); a[5] = fmaf(hi16(u0.z), c0, a[5]);
      a[6] = fmaf(lo16(u0.w), c0, a[6]); a[7] = fmaf(hi16(u0.w), c0, a[7]);
    }
    uint4 o;
    o.x = packbf(a[0], a[1]);
    o.y = packbf(a[2], a[3]);
    o.z = packbf(a[4], a[5]);
    o.w = packbf(a[6], a[7]);
    *(uint4*)&aggb[((size_t)r * NN + node) * 64 + l16 * 4] = o;
  }
}

// ---------------- prep 1: WWa1[r] = W[r] @ Wa1 (f32) ----------------
__global__ __launch_bounds__(256) void prep_wwa1_kernel(const float* __restrict__ W,
                                                        const float* __restrict__ Wa1,
                                                        float* __restrict__ WWa1) {
  int idx = blockIdx.x * 256 + threadIdx.x;       // r*16384 + i*128 + c
  if (idx >= NR * DD * DD) return;
  int r = idx >> 14, rem = idx & 16383, i = rem >> 7, c = rem & 127;
  const float* wrow = W + (r << 14) + (i << 7);
  float s = 0.f;
#pragma unroll 8
  for (int k = 0; k < DD; ++k) s = fmaf(wrow[k], Wa1[k * DD + c], s);
  WWa1[idx] = s;
}

// ---------------- prep 2: transpose + bf16 hi/lo split, COALESCED fragment layout -----
// New layout: [r][chunk(16)][n(128)][4 u32] so a 16-lane B-frag load is 256B contiguous.
__global__ __launch_bounds__(256) void prep_pack_kernel(const float* __restrict__ W,
                                                        const float* __restrict__ WWa1,
                                                        u32* __restrict__ wt_hi,
                                                        u32* __restrict__ wt_lo,
                                                        u32* __restrict__ wwt_hi) {
  int idx = blockIdx.x * 256 + threadIdx.x;       // r*8192 + n*64 + ku
  if (idx >= NR * DD * 64) return;
  int r = idx >> 13, rem = idx & 8191, n = rem >> 6, ku = rem & 63;
  int k0 = ku * 2;
  int oidx = (r << 13) + ((ku >> 2) << 9) + (n << 2) + (ku & 3);
  {
    const float* M = W + (r << 14);
    float w0 = M[k0 * DD + n], w1 = M[(k0 + 1) * DD + n];
    u32 h0 = bfr(w0), h1 = bfr(w1);
    float l0 = w0 - bf2f(h0), l1 = w1 - bf2f(h1);
    wt_hi[oidx] = h0 | (h1 << 16);
    wt_lo[oidx] = packbf(l0, l1);
  }
  {
    const float* M = WWa1 + (r << 14);
    float w0 = M[k0 * DD + n], w1 = M[(k0 + 1) * DD + n];
    wwt_hi[oidx] = bfr(w0) | (bfr(w1) << 16);
  }
}

// ---------------- prep 3: bsum[r][c] = (b_r @ Wa1)[c] + ba1[c] ----------------
__global__ __launch_bounds__(256) void prep_bsum_kernel(const float* __restrict__ b,
                                                        const float* __restrict__ Wa1,
                                                        const float* __restrict__ ba1,
                                                        float* __restrict__ bsum) {
  int idx = blockIdx.x * 256 + threadIdx.x;       // r*128 + c
  if (idx >= NR * DD) return;
  int r = idx >> 7, c = idx & 127;
  float s = ba1[c];
#pragma unroll 8
  for (int k = 0; k < DD; ++k) s = fmaf(b[r * DD + k], Wa1[k * DD + c], s);
  bsum[idx] = s;
}

#define MFMA(a, b, c) __builtin_amdgcn_mfma_f32_16x16x32_bf16((a), (b), (c), 0, 0, 0)

// ============ fused tail, 64-row blocks (small accumulators -> no spill) ==============
// Per r: stage A once; c2 = A@WWa1 -> score -> e_r = exp(score) (max-free, f32-safe,
// verified R10); c1 = A@W (hi+lo); fo += e_r*(rs*c1 + b_r). out = fo/sum(e).
__global__ __launch_bounds__(256, 2) void tail_fused_kernel(
    const u32* __restrict__ aggb, const u32* __restrict__ wt_hi,
    const u32* __restrict__ wt_lo, const u32* __restrict__ wwt_hi,
    const float* __restrict__ rs_in, const float* __restrict__ bias,
    const float* __restrict__ bsum, const float* __restrict__ wa2,
    float* __restrict__ out) {
  __shared__ u32 As[4160];        // staging: 4096 u32; epilogue: 32x130 f32 store tile
  __shared__ float scoreS[2][64];
  __shared__ float eLs[64];
  __shared__ float bL[NR][DD];
  const int tid = threadIdx.x;
  const int l = tid & 63, w = tid >> 6;
  const int wr = w >> 1, wc = w & 1;
  const int l15 = l & 15, lg = l >> 4;
  const int row0 = blockIdx.x * 64;

  for (int idx = tid; idx < NR * DD; idx += 256) bL[idx >> 7][idx & 127] = bias[idx];

  float wa2v[4];
#pragma unroll
  for (int nf = 0; nf < 4; ++nf) wa2v[nf] = wa2[wc * 64 + nf * 16 + l15];

  f4_t fo[2][4];
  float denom[2][4];
#pragma unroll
  for (int rf = 0; rf < 2; ++rf)
#pragma unroll
    for (int reg = 0; reg < 4; ++reg) {
      denom[rf][reg] = 0.f;
#pragma unroll
      for (int nf = 0; nf < 4; ++nf) fo[rf][nf][reg] = 0.f;
    }

  for (int r = 0; r < NR; ++r) {
    __syncthreads();   // As free to overwrite (covers bL visibility on r=0)
    const u32* Ar = aggb + (size_t)r * NN * 64;
#pragma unroll
    for (int it = 0; it < 4; ++it) {
      int s = it * 256 + tid;            // 16B-chunk slot 0..1023
      int row = s >> 4;                  // 0..63
      int c = (s & 15) ^ (row & 7);      // inverse-swizzled source chunk
      int grow = min(row0 + row, NN - 1);
      gload_lds16(Ar + (size_t)grow * 64 + c * 4, &As[it * 1024 + w * 256]);
    }
    __syncthreads();

    float rsv[2][4];
#pragma unroll
    for (int rf = 0; rf < 2; ++rf)
#pragma unroll
      for (int reg = 0; reg < 4; ++reg)
        rsv[rf][reg] = rs_in[r * NN + min(row0 + wr * 32 + rf * 16 + lg * 4 + reg, NN - 1)];

    // ---- c2 = A @ WWa1 (B coalesced from global, L2-hot) ----
    f4_t c2[2][4];
#pragma unroll
    for (int rf = 0; rf < 2; ++rf)
#pragma unroll
      for (int nf = 0; nf < 4; ++nf) c2[rf][nf] = (f4_t)0.f;
#pragma unroll
    for (int ks = 0; ks < 4; ++ks) {
      bf8_t a[2];
#pragma unroll
      for (int rf = 0; rf < 2; ++rf) {
        int m = wr * 32 + rf * 16 + l15;
        int ch = (ks * 4 + lg) ^ (m & 7);
        a[rf] = ldfrag(&As[m * 64 + ch * 4]);
      }
#pragma unroll
      for (int nf = 0; nf < 4; ++nf) {
        int n = wc * 64 + nf * 16 + l15;
        bf8_t gb = ldfrag(wwt_hi + (size_t)r * 8192 + (ks * 4 + lg) * 512 + n * 4);
#pragma unroll
        for (int rf = 0; rf < 2; ++rf) c2[rf][nf] = MFMA(a[rf], gb, c2[rf][nf]);
      }
    }

    // ---- score epilogue -> scoreS ----
#pragma unroll
    for (int rf = 0; rf < 2; ++rf) {
      float part[4] = {0.f, 0.f, 0.f, 0.f};
#pragma unroll
      for (int nf = 0; nf < 4; ++nf) {
        int col = wc * 64 + nf * 16 + l15;
        float bs = bsum[r * DD + col];
#pragma unroll
        for (int reg = 0; reg < 4; ++reg) {
          float t = fmaf(c2[rf][nf][reg], rsv[rf][reg], bs);
          t = fminf(fmaxf(t, -15.f), 15.f);
          float ex = __expf(2.f * t);
          part[reg] = fmaf((ex - 1.f) / (ex + 1.f), wa2v[nf], part[reg]);
        }
      }
#pragma unroll
      for (int reg = 0; reg < 4; ++reg) {
        float p = part[reg];
        p += __shfl_xor(p, 1);
        p += __shfl_xor(p, 2);
        p += __shfl_xor(p, 4);
        p += __shfl_xor(p, 8);
        if (l15 == 0) scoreS[wc][wr * 32 + rf * 16 + lg * 4 + reg] = p;
      }
    }
    __syncthreads();
    if (tid < 64) eLs[tid] = __expf(scoreS[0][tid] + scoreS[1][tid]);
    __syncthreads();

    float ev[2][4];
#pragma unroll
    for (int rf = 0; rf < 2; ++rf)
#pragma unroll
      for (int reg = 0; reg < 4; ++reg) {
        ev[rf][reg] = eLs[wr * 32 + rf * 16 + lg * 4 + reg];
        denom[rf][reg] += ev[rf][reg];
      }

    // ---- c1 = A @ W (hi + lo split) ----
    f4_t c1[2][4];
#pragma unroll
    for (int rf = 0; rf < 2; ++rf)
#pragma unroll
      for (int nf = 0; nf < 4; ++nf) c1[rf][nf] = (f4_t)0.f;
#pragma unroll
    for (int ks = 0; ks < 4; ++ks) {
      bf8_t a[2];
#pragma unroll
      for (int rf = 0; rf < 2; ++rf) {
        int m = wr * 32 + rf * 16 + l15;
        int ch = (ks * 4 + lg) ^ (m & 7);
        a[rf] = ldfrag(&As[m * 64 + ch * 4]);
      }
#pragma unroll
      for (int nf = 0; nf < 4; ++nf) {
        int n = wc * 64 + nf * 16 + l15;
        size_t bo = (size_t)r * 8192 + (ks * 4 + lg) * 512 + n * 4;
        bf8_t bh = ldfrag(wt_hi + bo);
        bf8_t bl = ldfrag(wt_lo + bo);
#pragma unroll
        for (int rf = 0; rf < 2; ++rf) c1[rf][nf] = MFMA(a[rf], bh, c1[rf][nf]);
#pragma unroll
        for (int rf = 0; rf < 2; ++rf) c1[rf][nf] = MFMA(a[rf], bl, c1[rf][nf]);
      }
    }

    // ---- fo += e*(rs*c1) + e*b ----
#pragma unroll
    for (int rf = 0; rf < 2; ++rf)
#pragma unroll
      for (int reg = 0; reg < 4; ++reg) {
        float er = ev[rf][reg] * rsv[rf][reg];
        float e = ev[rf][reg];
#pragma unroll
        for (int nf = 0; nf < 4; ++nf) {
          int col = wc * 64 + nf * 16 + l15;
          fo[rf][nf][reg] = fmaf(c1[rf][nf][reg], er, fo[rf][nf][reg]);
          fo[rf][nf][reg] = fmaf(bL[r][col], e, fo[rf][nf][reg]);
        }
      }
  }

  // ---- normalize + staged coalesced store (two 32-row halves via As tile) ----
  float inv[2][4];
#pragma unroll
  for (int rf = 0; rf < 2; ++rf)
#pragma unroll
    for (int reg = 0; reg < 4; ++reg) inv[rf][reg] = 1.f / denom[rf][reg];

  __syncthreads();   // all MFMA reads of As complete
  float* Asf = (float*)As;
  const int rloc = tid >> 3;          // 0..31
  const int c0 = (tid & 7) * 16;      // 0..112
#pragma unroll
  for (int half = 0; half < 2; ++half) {
    if (wr == half) {
#pragma unroll
      for (int rf = 0; rf < 2; ++rf)
#pragma unroll
        for (int nf = 0; nf < 4; ++nf)
#pragma unroll
          for (int reg = 0; reg < 4; ++reg)
            Asf[(rf * 16 + lg * 4 + reg) * 130 + wc * 64 + nf * 16 + l15] =
                fo[rf][nf][reg] * inv[rf][reg];
    }
    __syncthreads();
    int grow = row0 + half * 32 + rloc;
    if (grow < NN) {
#pragma unroll
      for (int j = 0; j < 4; ++j) {
        float4 v = *(const float4*)&Asf[rloc * 130 + c0 + j * 4];
        *(float4*)&out[(size_t)grow * DD + c0 + j * 4] = v;
      }
    }
    __syncthreads();
  }
}

extern "C" void kernel_launch(void* const* d_in, const int* in_sizes, int n_in,
                              void* d_out, int out_size, void* d_ws, size_t ws_size,
                              hipStream_t stream) {
  const float* x   = (const float*)d_in[0];
  const int*   src = (const int*)d_in[1];
  const int*   dst = (const int*)d_in[2];
  const float* W   = (const float*)d_in[3];
  const float* b   = (const float*)d_in[4];
  const float* Wa1 = (const float*)d_in[5];
  const float* ba1 = (const float*)d_in[6];
  const float* wa2 = (const float*)d_in[7];
  float* out = (float*)d_out;

  char* ws = (char*)d_ws;
  size_t off = 0;
  u32* aggb = (u32*)(ws + off); off += (size_t)NSEG * 64 * 4;   // 76.8 MB
  u32* xb   = (u32*)(ws + off); off += (size_t)NN * 64 * 4;     // 25.6 MB
  u32* bucketbuf = (u32*)(ws + off); off += (size_t)NR * NE * 4;  // 7.68 MB (exact)
  int* cntmat  = (int*)(ws + off); off += (size_t)NBLK2 * NBUK * 4;  // 2.2 MB
  int* cnt_out = (int*)(ws + off); off += (size_t)NSEG * 4;
  float* rs_out = (float*)(ws + off); off += (size_t)NSEG * 4;
  float* rs_in  = (float*)(ws + off); off += (size_t)NSEG * 4;
  int* btot       = (int*)(ws + off); off += (size_t)NBUK * 4;
  int* bucketbase = (int*)(ws + off); off += (size_t)(NBUK + 4) * 4;
  float* WWa1  = (float*)(ws + off); off += (size_t)NR * DD * DD * 4;
  u32* wt_hi   = (u32*)(ws + off); off += (size_t)NR * DD * 64 * 4;
  u32* wt_lo   = (u32*)(ws + off); off += (size_t)NR * DD * 64 * 4;
  u32* wwt_hi  = (u32*)(ws + off); off += (size_t)NR * DD * 64 * 4;
  float* bsum  = (float*)(ws + off); off += (size_t)NR * DD * 4;
  if (ws_size < off) return;  // fail loudly (output stays poisoned)

  hipMemsetAsync(cnt_out, 0, (size_t)NSEG * 4, stream);

  // weight prep (independent of graph chain)
  prep_wwa1_kernel<<<(NR * DD * DD + 255) / 256, 256, 0, stream>>>(W, Wa1, WWa1);
  prep_pack_kernel<<<(NR * DD * 64 + 255) / 256, 256, 0, stream>>>(W, WWa1, wt_hi, wt_lo,
                                                                   wwt_hi);
  prep_bsum_kernel<<<(NR * DD + 255) / 256, 256, 0, stream>>>(b, Wa1, ba1, bsum);

  convert_x_kernel<<<(NN * 64 + 255) / 256, 256, 0, stream>>>(x, xb);
  count_pass_kernel<<<NBLK2, 512, 0, stream>>>(src, dst, cnt_out, cntmat);
  rs_out_kernel<<<(NSEG + 255) / 256, 256, 0, stream>>>(cnt_out, rs_out);
  scan_blocks_kernel<<<NBUK, 256, 0, stream>>>(cntmat, btot);
  scan_buckets_kernel<<<1, 256, 0, stream>>>(btot, bucketbase);
  place_pass_kernel<<<NBLK2, 512, 0, stream>>>(src, dst, cntmat, bucketbase, bucketbuf);
  bucket_aggregate_kernel<<<NBUK, 256, 0, stream>>>(xb, bucketbuf, bucketbase, rs_out,
                                                    rs_in, aggb);

  tail_fused_kernel<<<(NN + 63) / 64, 256, 0, stream>>>(aggb, wt_hi, wt_lo, wwt_hi,
                                                        rs_in, b, bsum, wa2, out);
}

// Round 15
// 336.306 us; speedup vs baseline: 1.0431x; 1.0152x over previous
//
#include <hip/hip_runtime.h>

#define NN 100000
#define NE 640000
#define NR 3
#define DD 128
#define NSEG (NR * NN)            // 300000 segments (relation, node)
#define NBPR 782                  // buckets per relation (128 nodes each)
#define NBUK (NR * NBPR)          // 2346
#define BCAP 1280                 // per-bucket LDS staging cap (mean 819, sigma 28.6)
#define CHUNK 8192                // edges per partition block
#define NBLK2 ((NR * NE + CHUNK - 1) / CHUNK)   // 235

typedef unsigned int u32;
typedef short bf8_t __attribute__((ext_vector_type(8)));   // 8 bf16 (4 VGPRs)
typedef float f4_t __attribute__((ext_vector_type(4)));

union U4 { uint4 u; bf8_t b; };

__device__ __forceinline__ u32 bfr(float f) {          // f32 -> bf16 bits (RNE)
  u32 u = __float_as_uint(f);
  return (u + 0x7fffu + ((u >> 16) & 1u)) >> 16;
}
__device__ __forceinline__ u32 packbf(float a, float b) {
  return bfr(a) | (bfr(b) << 16);
}
__device__ __forceinline__ float lo16(u32 u) { return __uint_as_float(u << 16); }
__device__ __forceinline__ float hi16(u32 u) { return __uint_as_float(u & 0xffff0000u); }
__device__ __forceinline__ float bf2f(u32 bits) { return __uint_as_float(bits << 16); }

__device__ __forceinline__ bf8_t ldfrag(const u32* p) {
  U4 t; t.u = *(const uint4*)p; return t.b;
}

// async global->LDS, 16B per lane; dest = wave-uniform base + lane*16
__device__ __forceinline__ void gload_lds16(const u32* g, u32* l) {
  __builtin_amdgcn_global_load_lds((const __attribute__((address_space(1))) void*)g,
                                   (__attribute__((address_space(3))) void*)l, 16, 0, 0);
}

// ---------------- x -> packed bf16 ----------------
__global__ __launch_bounds__(256) void convert_x_kernel(const float* __restrict__ x,
                                                        u32* __restrict__ xb) {
  int i = blockIdx.x * 256 + threadIdx.x;
  if (i >= NN * 64) return;
  float2 v = ((const float2*)x)[i];
  xb[i] = packbf(v.x, v.y);
}

// ---------------- pass A: per-block bucket counts (LDS) + src-degree atomics ----------
__global__ __launch_bounds__(512) void count_pass_kernel(const int* __restrict__ src,
                                                         const int* __restrict__ dst,
                                                         int* __restrict__ cnt_out,
                                                         int* __restrict__ cntmat) {
  __shared__ int cnt[NBUK];
  const int tid = threadIdx.x;
  for (int i = tid; i < NBUK; i += 512) cnt[i] = 0;
  __syncthreads();
  const int base = blockIdx.x * CHUNK;
  const int end = min(base + CHUNK, NR * NE);
  for (int i = base + tid; i < end; i += 512) {
    int r = i / NE;
    atomicAdd(&cnt_out[r * NN + src[i]], 1);
    atomicAdd(&cnt[r * NBPR + (dst[i] >> 7)], 1);
  }
  __syncthreads();
  for (int i = tid; i < NBUK; i += 512) cntmat[blockIdx.x * NBUK + i] = cnt[i];
}

// ---------------- rs_out from cnt_out ----------------
__global__ __launch_bounds__(256) void rs_out_kernel(const int* __restrict__ cnt_out,
                                                     float* __restrict__ rs_out) {
  int i = blockIdx.x * 256 + threadIdx.x;
  if (i >= NSEG) return;
  int co = cnt_out[i]; if (co < 1) co = 1;
  rs_out[i] = rsqrtf((float)co);
}

// ---------------- scan across blocks (per bucket) -> cntmat becomes exclusive prefix --
__global__ __launch_bounds__(256) void scan_blocks_kernel(int* __restrict__ cntmat,
                                                          int* __restrict__ btot) {
  __shared__ int s[256];
  const int bk = blockIdx.x;
  const int t = threadIdx.x;
  int v = (t < NBLK2) ? cntmat[t * NBUK + bk] : 0;
  s[t] = v;
  __syncthreads();
  for (int d = 1; d < 256; d <<= 1) {
    int a = (t >= d) ? s[t - d] : 0;
    __syncthreads();
    s[t] += a;
    __syncthreads();
  }
  if (t < NBLK2) cntmat[t * NBUK + bk] = s[t] - v;   // exclusive within bucket
  if (t == 255) btot[bk] = s[255];
}

// ---------------- single-block exclusive scan over bucket totals ----------------
__global__ __launch_bounds__(256) void scan_buckets_kernel(const int* __restrict__ btot,
                                                           int* __restrict__ bucketbase) {
  __shared__ int s[256];
  const int tid = threadIdx.x;
  int v[10]; int loc = 0;
#pragma unroll
  for (int j = 0; j < 10; ++j) {
    int idx = tid * 10 + j;
    int c = (idx < NBUK) ? btot[idx] : 0;
    v[j] = c; loc += c;
  }
  s[tid] = loc;
  __syncthreads();
  for (int d = 1; d < 256; d <<= 1) {
    int t = (tid >= d) ? s[tid - d] : 0;
    __syncthreads();
    s[tid] += t;
    __syncthreads();
  }
  int run = s[tid] - loc;   // exclusive prefix
#pragma unroll
  for (int j = 0; j < 10; ++j) {
    int idx = tid * 10 + j;
    if (idx < NBUK) bucketbase[idx] = run;
    run += v[j];
  }
  if (tid == 255) bucketbase[NBUK] = s[255];
}

// ---------------- pass B: deterministic placement into bucket-grouped payload ---------
__global__ __launch_bounds__(512) void place_pass_kernel(const int* __restrict__ src,
                                                         const int* __restrict__ dst,
                                                         const int* __restrict__ cntmat,
                                                         const int* __restrict__ bucketbase,
                                                         u32* __restrict__ bucketbuf) {
  __shared__ int cur[NBUK];
  const int tid = threadIdx.x;
  for (int i = tid; i < NBUK; i += 512)
    cur[i] = bucketbase[i] + cntmat[blockIdx.x * NBUK + i];
  __syncthreads();
  const int base = blockIdx.x * CHUNK;
  const int end = min(base + CHUNK, NR * NE);
  for (int i = base + tid; i < end; i += 512) {
    int r = i / NE;
    int d = dst[i];
    int bk = r * NBPR + (d >> 7);
    int pos = atomicAdd(&cur[bk], 1);       // LDS returning atomic, low contention
    bucketbuf[pos] = (u32)src[i] | ((u32)(d & 127) << 17);
  }
}

// ---------------- fused: in-bucket counting sort + rs_in + gather aggregate -----------
__global__ __launch_bounds__(256) void bucket_aggregate_kernel(
    const u32* __restrict__ xb, const u32* __restrict__ bucketbuf,
    const int* __restrict__ bucketbase, const float* __restrict__ rs_out,
    float* __restrict__ rs_in, u32* __restrict__ aggb) {
  __shared__ u32 eL[BCAP];
  __shared__ u32 sorted[BCAP];
  __shared__ int cntA[128], prefE[128], cur[128];
  const int tid = threadIdx.x;
  const int bk = blockIdx.x;
  const int r = bk / NBPR, bidx = bk % NBPR;
  const int node0 = bidx * 128;
  const int base = bucketbase[bk];
  const int count = min(bucketbase[bk + 1] - base, BCAP);
  if (tid < 128) cntA[tid] = 0;
  for (int i = tid; i < count; i += 256) eL[i] = bucketbuf[base + i];
  __syncthreads();
  for (int i = tid; i < count; i += 256) atomicAdd(&cntA[eL[i] >> 17], 1);
  __syncthreads();
  if (tid < 128) prefE[tid] = cntA[tid];
  __syncthreads();
  for (int d = 1; d < 128; d <<= 1) {
    int v = 0;
    if (tid < 128 && tid >= d) v = prefE[tid - d];
    __syncthreads();
    if (tid < 128) prefE[tid] += v;
    __syncthreads();
  }
  if (tid < 128) {
    int excl = prefE[tid] - cntA[tid];
    prefE[tid] = excl;
    cur[tid] = excl;
    int node = node0 + tid;
    if (node < NN) rs_in[r * NN + node] = rsqrtf((float)max(cntA[tid], 1));
  }
  __syncthreads();
  for (int i = tid; i < count; i += 256) {
    u32 v = eL[i];
    int pos = atomicAdd(&cur[v >> 17], 1);
    sorted[pos] = v & 0x1FFFFu;
  }
  __syncthreads();

  // gather-aggregate: 16-lane groups, one node at a time, register f32 accum
  const int l16 = tid & 15, g = tid >> 4;
  const float* rsb = rs_out + r * NN;
  for (int nn = g; nn < 128; nn += 16) {
    const int node = node0 + nn;
    if (node >= NN) continue;
    const int beg = prefE[nn], cE = cntA[nn];
    float a[8] = {0.f, 0.f, 0.f, 0.f, 0.f, 0.f, 0.f, 0.f};
    int e = 0;
    for (; e + 1 < cE; e += 2) {
      int s0 = (int)sorted[beg + e], s1 = (int)sorted[beg + e + 1];
      float c0 = rsb[s0], c1 = rsb[s1];
      uint4 u0 = *(const uint4*)&xb[(size_t)s0 * 64 + l16 * 4];
      uint4 u1 = *(const uint4*)&xb[(size_t)s1 * 64 + l16 * 4];
      a[0] = fmaf(lo16(u0.x), c0, a[0]); a[1] = fmaf(hi16(u0.x), c0, a[1]);
      a[2] = fmaf(lo16(u0.y), c0, a[2]); a[3] = fmaf(hi16(u0.y), c0, a[3]);
      a[4] = fmaf(lo16(u0.z), c0, a[4]); a[5] = fmaf(hi16(u0.z), c0, a[5]);
      a[6] = fmaf(lo16(u0.w), c0, a[6]); a[7] = fmaf(hi16(u0.w), c0, a[7]);
      a[0] = fmaf(lo16(u1.x), c1, a[0]); a[1] = fmaf(hi16(u1.x), c1, a[1]);
      a[2] = fmaf(lo16(u1.y), c1, a[2]); a[3] = fmaf(hi16(u1.y), c1, a[3]);
      a[4] = fmaf(lo16(u1.z), c1, a[4]); a[5] = fmaf(hi16(u1.z), c1, a[5]);
      a[6] = fmaf(lo16(u1.w), c1, a[6]); a[7] = fmaf(hi16(u1.w), c1, a[7]);
    }
    if (e < cE) {
      int s0 = (int)sorted[beg + e];
      float c0 = rsb[s0];
      uint4 u0 = *(const uint4*)&xb[(size_t)s0 * 64 + l16 * 4];
      a[0] = fmaf(lo16(u0.x), c0, a[0]); a[1] = fmaf(hi16(u0.x), c0, a[1]);
      a[2] = fmaf(lo16(u0.y), c0, a[2]); a[3] = fmaf(hi16(u0.y), c0, a[3]);
      a[4] = fmaf(lo16(u0.z), c0, a[4]); a[5] = fmaf(hi16(u0.z), c0, a[5]);
      a[6] = fmaf(lo16(u0.w), c0, a[6]); a[7] = fmaf(hi16(u0.w), c0, a[7]);
    }
    uint4 o;
    o.x = packbf(a[0], a[1]);
    o.y = packbf(a[2], a[3]);
    o.z = packbf(a[4], a[5]);
    o.w = packbf(a[6], a[7]);
    *(uint4*)&aggb[((size_t)r * NN + node) * 64 + l16 * 4] = o;
  }
}

// ---------------- prep 1: WWa1[r] = W[r] @ Wa1 (f32) ----------------
__global__ __launch_bounds__(256) void prep_wwa1_kernel(const float* __restrict__ W,
                                                        const float* __restrict__ Wa1,
                                                        float* __restrict__ WWa1) {
  int idx = blockIdx.x * 256 + threadIdx.x;       // r*16384 + i*128 + c
  if (idx >= NR * DD * DD) return;
  int r = idx >> 14, rem = idx & 16383, i = rem >> 7, c = rem & 127;
  const float* wrow = W + (r << 14) + (i << 7);
  float s = 0.f;
#pragma unroll 8
  for (int k = 0; k < DD; ++k) s = fmaf(wrow[k], Wa1[k * DD + c], s);
  WWa1[idx] = s;
}

// ---------------- prep 2: transpose + bf16 hi/lo split, COALESCED fragment layout -----
// Layout: [r][chunk(16)][n(128)][4 u32] so a 16-lane B-frag load is 256B contiguous.
__global__ __launch_bounds__(256) void prep_pack_kernel(const float* __restrict__ W,
                                                        const float* __restrict__ WWa1,
                                                        u32* __restrict__ wt_hi,
                                                        u32* __restrict__ wt_lo,
                                                        u32* __restrict__ wwt_hi) {
  int idx = blockIdx.x * 256 + threadIdx.x;       // r*8192 + n*64 + ku
  if (idx >= NR * DD * 64) return;
  int r = idx >> 13, rem = idx & 8191, n = rem >> 6, ku = rem & 63;
  int k0 = ku * 2;
  int oidx = (r << 13) + ((ku >> 2) << 9) + (n << 2) + (ku & 3);
  {
    const float* M = W + (r << 14);
    float w0 = M[k0 * DD + n], w1 = M[(k0 + 1) * DD + n];
    u32 h0 = bfr(w0), h1 = bfr(w1);
    float l0 = w0 - bf2f(h0), l1 = w1 - bf2f(h1);
    wt_hi[oidx] = h0 | (h1 << 16);
    wt_lo[oidx] = packbf(l0, l1);
  }
  {
    const float* M = WWa1 + (r << 14);
    float w0 = M[k0 * DD + n], w1 = M[(k0 + 1) * DD + n];
    wwt_hi[oidx] = bfr(w0) | (bfr(w1) << 16);
  }
}

// ---------------- prep 3: bsum[r][c] = (b_r @ Wa1)[c] + ba1[c] ----------------
__global__ __launch_bounds__(256) void prep_bsum_kernel(const float* __restrict__ b,
                                                        const float* __restrict__ Wa1,
                                                        const float* __restrict__ ba1,
                                                        float* __restrict__ bsum) {
  int idx = blockIdx.x * 256 + threadIdx.x;       // r*128 + c
  if (idx >= NR * DD) return;
  int r = idx >> 7, c = idx & 127;
  float s = ba1[c];
#pragma unroll 8
  for (int k = 0; k < DD; ++k) s = fmaf(b[r * DD + k], Wa1[k * DD + c], s);
  bsum[idx] = s;
}

#define MFMA(a, b, c) __builtin_amdgcn_mfma_f32_16x16x32_bf16((a), (b), (c), 0, 0, 0)

// ============ fused tail, 64-row blocks, double-buffered A prefetch ==============
// Per r: c2 = A@WWa1 -> score -> e_r = exp(score) (max-free, f32-safe, verified R10);
// prefetch A(r+1) issued before c1 so it rides under the c1 GEMM; 2 barriers per r.
__global__ __launch_bounds__(256, 2) void tail_fused_kernel(
    const u32* __restrict__ aggb, const u32* __restrict__ wt_hi,
    const u32* __restrict__ wt_lo, const u32* __restrict__ wwt_hi,
    const float* __restrict__ rs_in, const float* __restrict__ bias,
    const float* __restrict__ bsum, const float* __restrict__ wa2,
    float* __restrict__ out) {
  __shared__ u32 As[2][4224];     // double-buffer staging; buf0 reused as store tile
  __shared__ float scoreS[2][64];
  __shared__ float bL[NR][DD];
  const int tid = threadIdx.x;
  const int l = tid & 63, w = tid >> 6;
  const int wr = w >> 1, wc = w & 1;
  const int l15 = l & 15, lg = l >> 4;
  const int row0 = blockIdx.x * 64;

  // stage slot for this thread (same mapping as reads: As[buf][4*s], s=it*256+tid)
  const int srow = tid >> 4;                 // 0..15 within each it-group of 16 rows
  // prologue: issue stage of r=0 into buf0
  {
    const u32* Ar = aggb;
#pragma unroll
    for (int it = 0; it < 4; ++it) {
      int s = it * 256 + tid;
      int row = s >> 4;
      int c = (s & 15) ^ (row & 7);
      int grow = min(row0 + row, NN - 1);
      gload_lds16(Ar + (size_t)grow * 64 + c * 4, &As[0][it * 1024 + w * 256]);
    }
  }
  for (int idx = tid; idx < NR * DD; idx += 256) bL[idx >> 7][idx & 127] = bias[idx];
  (void)srow;

  float wa2v[4];
#pragma unroll
  for (int nf = 0; nf < 4; ++nf) wa2v[nf] = wa2[wc * 64 + nf * 16 + l15];

  f4_t fo[2][4];
  float denom[2][4];
#pragma unroll
  for (int rf = 0; rf < 2; ++rf)
#pragma unroll
    for (int reg = 0; reg < 4; ++reg) {
      denom[rf][reg] = 0.f;
#pragma unroll
      for (int nf = 0; nf < 4; ++nf) fo[rf][nf][reg] = 0.f;
    }

  __syncthreads();   // buf0 staged (vmcnt drained) + bL visible

  int cur = 0;
  for (int r = 0; r < NR; ++r) {
    const u32* Ab = &As[cur][0];

    float rsv[2][4];
#pragma unroll
    for (int rf = 0; rf < 2; ++rf)
#pragma unroll
      for (int reg = 0; reg < 4; ++reg)
        rsv[rf][reg] = rs_in[r * NN + min(row0 + wr * 32 + rf * 16 + lg * 4 + reg, NN - 1)];

    // ---- c2 = A @ WWa1 (B coalesced from global, L2-hot) ----
    f4_t c2[2][4];
#pragma unroll
    for (int rf = 0; rf < 2; ++rf)
#pragma unroll
      for (int nf = 0; nf < 4; ++nf) c2[rf][nf] = (f4_t)0.f;
#pragma unroll
    for (int ks = 0; ks < 4; ++ks) {
      bf8_t a[2];
#pragma unroll
      for (int rf = 0; rf < 2; ++rf) {
        int m = wr * 32 + rf * 16 + l15;
        int ch = (ks * 4 + lg) ^ (m & 7);
        a[rf] = ldfrag(&Ab[m * 64 + ch * 4]);
      }
#pragma unroll
      for (int nf = 0; nf < 4; ++nf) {
        int n = wc * 64 + nf * 16 + l15;
        bf8_t gb = ldfrag(wwt_hi + (size_t)r * 8192 + (ks * 4 + lg) * 512 + n * 4);
#pragma unroll
        for (int rf = 0; rf < 2; ++rf) c2[rf][nf] = MFMA(a[rf], gb, c2[rf][nf]);
      }
    }

    // ---- score epilogue -> scoreS ----
#pragma unroll
    for (int rf = 0; rf < 2; ++rf) {
      float part[4] = {0.f, 0.f, 0.f, 0.f};
#pragma unroll
      for (int nf = 0; nf < 4; ++nf) {
        int col = wc * 64 + nf * 16 + l15;
        float bs = bsum[r * DD + col];
#pragma unroll
        for (int reg = 0; reg < 4; ++reg) {
          float t = fmaf(c2[rf][nf][reg], rsv[rf][reg], bs);
          t = fminf(fmaxf(t, -15.f), 15.f);
          float ex = __expf(2.f * t);
          part[reg] = fmaf((ex - 1.f) / (ex + 1.f), wa2v[nf], part[reg]);
        }
      }
#pragma unroll
      for (int reg = 0; reg < 4; ++reg) {
        float p = part[reg];
        p += __shfl_xor(p, 1);
        p += __shfl_xor(p, 2);
        p += __shfl_xor(p, 4);
        p += __shfl_xor(p, 8);
        if (l15 == 0) scoreS[wc][wr * 32 + rf * 16 + lg * 4 + reg] = p;
      }
    }
    __syncthreads();   // scoreS visible (prefetch of r not yet issued -> cheap drain)

    // ---- issue prefetch of A(r+1) into the other buffer; rides under c1 ----
    if (r + 1 < NR) {
      const u32* Arn = aggb + (size_t)(r + 1) * NN * 64;
#pragma unroll
      for (int it = 0; it < 4; ++it) {
        int s = it * 256 + tid;
        int row = s >> 4;
        int c = (s & 15) ^ (row & 7);
        int grow = min(row0 + row, NN - 1);
        gload_lds16(Arn + (size_t)grow * 64 + c * 4, &As[cur ^ 1][it * 1024 + w * 256]);
      }
    }

    // ---- e = exp(score) per thread (max-free softmax) ----
    float ev[2][4];
#pragma unroll
    for (int rf = 0; rf < 2; ++rf)
#pragma unroll
      for (int reg = 0; reg < 4; ++reg) {
        int idx = wr * 32 + rf * 16 + lg * 4 + reg;
        ev[rf][reg] = __expf(scoreS[0][idx] + scoreS[1][idx]);
        denom[rf][reg] += ev[rf][reg];
      }

    // ---- c1 = A @ W (hi + lo split) ----
    f4_t c1[2][4];
#pragma unroll
    for (int rf = 0; rf < 2; ++rf)
#pragma unroll
      for (int nf = 0; nf < 4; ++nf) c1[rf][nf] = (f4_t)0.f;
#pragma unroll
    for (int ks = 0; ks < 4; ++ks) {
      bf8_t a[2];
#pragma unroll
      for (int rf = 0; rf < 2; ++rf) {
        int m = wr * 32 + rf * 16 + l15;
        int ch = (ks * 4 + lg) ^ (m & 7);
        a[rf] = ldfrag(&Ab[m * 64 + ch * 4]);
      }
#pragma unroll
      for (int nf = 0; nf < 4; ++nf) {
        int n = wc * 64 + nf * 16 + l15;
        size_t bo = (size_t)r * 8192 + (ks * 4 + lg) * 512 + n * 4;
        bf8_t bh = ldfrag(wt_hi + bo);
        bf8_t bl = ldfrag(wt_lo + bo);
#pragma unroll
        for (int rf = 0; rf < 2; ++rf) c1[rf][nf] = MFMA(a[rf], bh, c1[rf][nf]);
#pragma unroll
        for (int rf = 0; rf < 2; ++rf) c1[rf][nf] = MFMA(a[rf], bl, c1[rf][nf]);
      }
    }

    // ---- fo += e*(rs*c1) + e*b ----
#pragma unroll
    for (int rf = 0; rf < 2; ++rf)
#pragma unroll
      for (int reg = 0; reg < 4; ++reg) {
        float er = ev[rf][reg] * rsv[rf][reg];
        float e = ev[rf][reg];
#pragma unroll
        for (int nf = 0; nf < 4; ++nf) {
          int col = wc * 64 + nf * 16 + l15;
          fo[rf][nf][reg] = fmaf(c1[rf][nf][reg], er, fo[rf][nf][reg]);
          fo[rf][nf][reg] = fmaf(bL[r][col], e, fo[rf][nf][reg]);
        }
      }

    __syncthreads();   // next buffer staged (drain) + scoreS safe to overwrite
    cur ^= 1;
  }

  // ---- normalize + staged coalesced store (two 32-row halves via As[0] tile) ----
  float inv[2][4];
#pragma unroll
  for (int rf = 0; rf < 2; ++rf)
#pragma unroll
    for (int reg = 0; reg < 4; ++reg) inv[rf][reg] = 1.f / denom[rf][reg];

  float* Asf = (float*)&As[0][0];     // 4224 floats >= 32*130
  const int rloc = tid >> 3;          // 0..31
  const int c0 = (tid & 7) * 16;      // 0..112
#pragma unroll
  for (int half = 0; half < 2; ++half) {
    if (wr == half) {
#pragma unroll
      for (int rf = 0; rf < 2; ++rf)
#pragma unroll
        for (int nf = 0; nf < 4; ++nf)
#pragma unroll
          for (int reg = 0; reg < 4; ++reg)
            Asf[(rf * 16 + lg * 4 + reg) * 130 + wc * 64 + nf * 16 + l15] =
                fo[rf][nf][reg] * inv[rf][reg];
    }
    __syncthreads();
    int grow = row0 + half * 32 + rloc;
    if (grow < NN) {
#pragma unroll
      for (int j = 0; j < 4; ++j) {
        float4 v = *(const float4*)&Asf[rloc * 130 + c0 + j * 4];
        *(float4*)&out[(size_t)grow * DD + c0 + j * 4] = v;
      }
    }
    __syncthreads();
  }
}

extern "C" void kernel_launch(void* const* d_in, const int* in_sizes, int n_in,
                              void* d_out, int out_size, void* d_ws, size_t ws_size,
                              hipStream_t stream) {
  const float* x   = (const float*)d_in[0];
  const int*   src = (const int*)d_in[1];
  const int*   dst = (const int*)d_in[2];
  const float* W   = (const float*)d_in[3];
  const float* b   = (const float*)d_in[4];
  const float* Wa1 = (const float*)d_in[5];
  const float* ba1 = (const float*)d_in[6];
  const float* wa2 = (const float*)d_in[7];
  float* out = (float*)d_out;

  char* ws = (char*)d_ws;
  size_t off = 0;
  u32* aggb = (u32*)(ws + off); off += (size_t)NSEG * 64 * 4;   // 76.8 MB
  u32* xb   = (u32*)(ws + off); off += (size_t)NN * 64 * 4;     // 25.6 MB
  u32* bucketbuf = (u32*)(ws + off); off += (size_t)NR * NE * 4;  // 7.68 MB (exact)
  int* cntmat  = (int*)(ws + off); off += (size_t)NBLK2 * NBUK * 4;  // 2.2 MB
  int* cnt_out = (int*)(ws + off); off += (size_t)NSEG * 4;
  float* rs_out = (float*)(ws + off); off += (size_t)NSEG * 4;
  float* rs_in  = (float*)(ws + off); off += (size_t)NSEG * 4;
  int* btot       = (int*)(ws + off); off += (size_t)NBUK * 4;
  int* bucketbase = (int*)(ws + off); off += (size_t)(NBUK + 4) * 4;
  float* WWa1  = (float*)(ws + off); off += (size_t)NR * DD * DD * 4;
  u32* wt_hi   = (u32*)(ws + off); off += (size_t)NR * DD * 64 * 4;
  u32* wt_lo   = (u32*)(ws + off); off += (size_t)NR * DD * 64 * 4;
  u32* wwt_hi  = (u32*)(ws + off); off += (size_t)NR * DD * 64 * 4;
  float* bsum  = (float*)(ws + off); off += (size_t)NR * DD * 4;
  if (ws_size < off) return;  // fail loudly (output stays poisoned)

  hipMemsetAsync(cnt_out, 0, (size_t)NSEG * 4, stream);

  // weight prep (independent of graph chain)
  prep_wwa1_kernel<<<(NR * DD * DD + 255) / 256, 256, 0, stream>>>(W, Wa1, WWa1);
  prep_pack_kernel<<<(NR * DD * 64 + 255) / 256, 256, 0, stream>>>(W, WWa1, wt_hi, wt_lo,
                                                                   wwt_hi);
  prep_bsum_kernel<<<(NR * DD + 255) / 256, 256, 0, stream>>>(b, Wa1, ba1, bsum);

  convert_x_kernel<<<(NN * 64 + 255) / 256, 256, 0, stream>>>(x, xb);
  count_pass_kernel<<<NBLK2, 512, 0, stream>>>(src, dst, cnt_out, cntmat);
  rs_out_kernel<<<(NSEG + 255) / 256, 256, 0, stream>>>(cnt_out, rs_out);
  scan_blocks_kernel<<<NBUK, 256, 0, stream>>>(cntmat, btot);
  scan_buckets_kernel<<<1, 256, 0, stream>>>(btot, bucketbase);
  place_pass_kernel<<<NBLK2, 512, 0, stream>>>(src, dst, cntmat, bucketbase, bucketbuf);
  bucket_aggregate_kernel<<<NBUK, 256, 0, stream>>>(xb, bucketbuf, bucketbase, rs_out,
                                                    rs_in, aggb);

  tail_fused_kernel<<<(NN + 63) / 64, 256, 0, stream>>>(aggb, wt_hi, wt_lo, wwt_hi,
                                                        rs_in, b, bsum, wa2, out);
}